// Round 1
// baseline (300.049 us; speedup 1.0000x reference)
//
#include <hip/hip_runtime.h>
#include <math.h>

#define NFFT 512
#define NBINS 257          // NFFT/2 + 1
#define NFILT 64
#define FRAME_LEN 400
#define FRAME_STEP 160

// One 256-thread block per frame.
// LDS: re/im[512] FFT workspace, 256-entry twiddle table, 257-entry power
// spectrum, 4x64 matmul partials.  Total ~8.3 KB -> LDS not an occupancy limit.
__global__ __launch_bounds__(256) void fbank_kernel(const float* __restrict__ x,
                                                    const float* __restrict__ filters,
                                                    float* __restrict__ out) {
    __shared__ float re[NFFT];
    __shared__ float im[NFFT];
    __shared__ float twr[NFFT / 2];
    __shared__ float twi[NFFT / 2];
    __shared__ float pw[NBINS + 3];
    __shared__ float psum[4][NFILT];

    const int t = threadIdx.x;
    const int frame = blockIdx.x;
    const long base = (long)frame * FRAME_STEP;

    // ---- twiddle table: w_m = exp(-2*pi*i*m/512), m in [0,256) ----
    {
        float ang = -2.0f * (float)M_PI * (float)t * (1.0f / (float)NFFT);
        twr[t] = cosf(ang);
        twi[t] = sinf(ang);
    }

    // ---- load frame with pre-emphasis, scatter to bit-reversed position ----
    // pre[g] = x[g] - 0.97*x[g-1], except pre[0] = x[0] (global, not per-frame)
    for (int src = t; src < NFFT; src += 256) {
        float v = 0.0f;
        if (src < FRAME_LEN) {
            long g = base + src;
            float cur = x[g];
            v = (g == 0) ? cur : (cur - 0.97f * x[g - 1]);
        }
        int dst = (int)(__brev((unsigned)src) >> 23);  // 9-bit reversal
        re[dst] = v;
        im[dst] = 0.0f;
    }
    __syncthreads();

    // ---- in-place radix-2 DIT FFT, 9 stages, 256 butterflies/stage ----
#pragma unroll
    for (int s = 0; s < 9; s++) {
        const int half = 1 << s;
        const int pos = t & (half - 1);
        const int i0 = ((t >> s) << (s + 1)) + pos;
        const int i1 = i0 + half;
        const int m = pos << (8 - s);  // twiddle index
        const float wr = twr[m], wi = twi[m];
        const float ar = re[i0], ai = im[i0];
        const float br = re[i1], bi = im[i1];
        const float tr = wr * br - wi * bi;
        const float ti = wr * bi + wi * br;
        re[i0] = ar + tr;
        im[i0] = ai + ti;
        re[i1] = ar - tr;
        im[i1] = ai - ti;
        __syncthreads();
    }

    // ---- power spectrum, bins 0..256 ----
    for (int k = t; k < NBINS; k += 256) {
        float a = re[k], b = im[k];
        pw[k] = (a * a + b * b) * (1.0f / (float)NFFT);
    }
    __syncthreads();

    // ---- mel filterbank: feat[n] = sum_k pw[k] * F[k][n]  (F is 257x64) ----
    const int n = t & 63;
    const int part = t >> 6;  // 4 k-partitions
    float acc = 0.0f;
    for (int k = part; k < NBINS; k += 4) {
        acc += pw[k] * filters[k * NFILT + n];
    }
    psum[part][n] = acc;
    __syncthreads();

    // ---- per-frame normalize (population std over the 64 mel bins) ----
    if (t < 64) {
        float f = psum[0][t] + psum[1][t] + psum[2][t] + psum[3][t] + 1e-30f;
        float sum = f;
#pragma unroll
        for (int mk = 1; mk < 64; mk <<= 1) sum += __shfl_xor(sum, mk, 64);
        const float mean = sum * (1.0f / 64.0f);
        const float d = f - mean;
        float v = d * d;
#pragma unroll
        for (int mk = 1; mk < 64; mk <<= 1) v += __shfl_xor(v, mk, 64);
        const float sd = sqrtf(v * (1.0f / 64.0f));
        out[(long)frame * NFILT + t] = (f - mean) / sd;
    }
}

extern "C" void kernel_launch(void* const* d_in, const int* in_sizes, int n_in,
                              void* d_out, int out_size, void* d_ws, size_t ws_size,
                              hipStream_t stream) {
    const float* x = (const float*)d_in[0];
    const float* filters = (const float*)d_in[1];
    float* out = (float*)d_out;
    const int num_frames = out_size / NFILT;  // 50000
    fbank_kernel<<<num_frames, 256, 0, stream>>>(x, filters, out);
}

// Round 2
// 111.890 us; speedup vs baseline: 2.6816x; 2.6816x over previous
//
#include <hip/hip_runtime.h>
#include <math.h>

#define NFILT 64
#define FRAME_LEN 400
#define FRAME_STEP 160
#define WMAX 24            // max nonzero span of one mel filter (actual max ~21)
#define WAVES 4            // waves per block (256 threads)
#define NBLOCKS 1024

// One wave = one frame at a time. 512-pt FFT = per-lane radix-8 x cross-lane
// 64-pt shuffle FFT. No __syncthreads after setup; LDS only holds the 260-entry
// power spectrum per wave (+pad) -> no bank conflicts anywhere.
__global__ __launch_bounds__(256) void fbank_kernel(const float* __restrict__ x,
                                                    const float* __restrict__ filters,
                                                    float* __restrict__ out,
                                                    int num_frames, int fpw) {
    __shared__ float pw[WAVES][280];
    const int t = threadIdx.x;
    const int l = t & 63;              // lane
    const int w = t >> 6;              // wave in block
    float* pwrow = pw[w];

    // zero the pad region [257,280) once (only bins <=256 are ever written)
    for (int i = 257 + l; i < 280; i += 64) pwrow[i] = 0.0f;

    // ---- per-lane mel filter window, taken verbatim from the input filters ----
    // filters is (257,64): column l = filter l, nonzero on a <=21-bin window.
    int lo = 257;
    for (int k = 0; k < 257; k++) {
        float fv = filters[k * NFILT + l];
        if (fv != 0.0f && lo == 257) lo = k;
    }
    if (lo > 256) lo = 256;            // unreachable safety clamp
    float wc[WMAX];
#pragma unroll
    for (int i = 0; i < WMAX; i++) {
        int k = lo + i;
        wc[i] = (k <= 256) ? filters[k * NFILT + l] : 0.0f;  // zeros beyond span
    }

    // ---- loop-invariant twiddles (registers, once per block) ----
    const int rl = (int)(__brev((unsigned)l) >> 26);   // rev6(lane) = k1
    float cA[6], sA[6], sg[6];
#pragma unroll
    for (int j = 0; j < 6; j++) {
        const int d = 32 >> j;
        const int hi = l & d;
        float th = -2.0f * (float)M_PI * (float)(l & (d - 1)) / (float)(2 * d);
        cA[j] = hi ? cosf(th) : 1.0f;
        sA[j] = hi ? sinf(th) : 0.0f;
        sg[j] = hi ? -1.0f : 1.0f;
    }
    float br[8], bi[8];                 // W_512^{n2*k1}, n2=0..7
    {
        float th = -2.0f * (float)M_PI * (float)rl * (1.0f / 512.0f);
        float c1 = cosf(th), s1 = sinf(th);
        br[0] = 1.0f; bi[0] = 0.0f; br[1] = c1; bi[1] = s1;
#pragma unroll
        for (int r = 2; r < 8; r++) {
            float pr_ = br[r - 1], pi_ = bi[r - 1];
            br[r] = pr_ * c1 - pi_ * s1;
            bi[r] = pr_ * s1 + pi_ * c1;
        }
    }

    const int gw = blockIdx.x * WAVES + w;       // global wave id
    const long f0 = (long)gw * fpw;
    const long fend = (f0 + fpw < num_frames) ? f0 + fpw : num_frames;

    for (long f = f0; f < fend; f++) {
        const long base = f * FRAME_STEP;

        // ---- load 8 contiguous samples/lane + pre-emphasis ----
        float a0=0,a1=0,a2=0,a3=0,a4=0,a5=0,a6=0,a7=0;
        if (l < 50) {                                   // 8*50 = 400 = FRAME_LEN
            const float4* p4 = reinterpret_cast<const float4*>(x + base + 8 * l);
            float4 A = p4[0], B = p4[1];
            a0=A.x; a1=A.y; a2=A.z; a3=A.w; a4=B.x; a5=B.y; a6=B.z; a7=B.w;
        }
        float prev = __shfl_up(a7, 1, 64);
        if (l == 0) prev = (base > 0) ? x[base - 1] : 0.0f;  // g==0 -> x[0]-0.97*0

        float vr[8], vi[8];
        vr[0] = (l < 50) ? fmaf(-0.97f, prev, a0) : 0.0f;
        vr[1] = (l < 50) ? fmaf(-0.97f, a0, a1) : 0.0f;
        vr[2] = (l < 50) ? fmaf(-0.97f, a1, a2) : 0.0f;
        vr[3] = (l < 50) ? fmaf(-0.97f, a2, a3) : 0.0f;
        vr[4] = (l < 50) ? fmaf(-0.97f, a3, a4) : 0.0f;
        vr[5] = (l < 50) ? fmaf(-0.97f, a4, a5) : 0.0f;
        vr[6] = (l < 50) ? fmaf(-0.97f, a5, a6) : 0.0f;
        vr[7] = (l < 50) ? fmaf(-0.97f, a6, a7) : 0.0f;

        // ---- cross-lane 64-pt DIF FFT (6 shuffle stages) ----
        // stage 0 specialized: imag parts are all zero
#pragma unroll
        for (int r = 0; r < 8; r++) {
            float pr = __shfl_xor(vr[r], 32, 64);
            float tr = fmaf(sg[0], vr[r], pr);
            vr[r] = tr * cA[0];
            vi[r] = tr * sA[0];
        }
#pragma unroll
        for (int j = 1; j < 6; j++) {
            const int d = 32 >> j;
            const float c = cA[j], s = sA[j], g = sg[j];
#pragma unroll
            for (int r = 0; r < 8; r++) {
                float pr = __shfl_xor(vr[r], d, 64);
                float pi = __shfl_xor(vi[r], d, 64);
                float tr = fmaf(g, vr[r], pr);
                float ti = fmaf(g, vi[r], pi);
                vr[r] = tr * c - ti * s;
                vi[r] = tr * s + ti * c;
            }
        }
        // lane l now holds A[k1 = rev6(l)] for each sample-group n2 = r

        // ---- twiddle W_512^{n2*k1} ----
#pragma unroll
        for (int r = 1; r < 8; r++) {
            float tr = vr[r], ti = vi[r];
            vr[r] = tr * br[r] - ti * bi[r];
            vi[r] = tr * bi[r] + ti * br[r];
        }

        // ---- in-register 8-pt DIF FFT over n2 ----
        const float RH = 0.70710678118654752f;
        {   // stage M=8 (pairs r, r+4), twiddles W8^{0..3}
            float t0r=vr[0]+vr[4], t0i=vi[0]+vi[4];
            float d0r=vr[0]-vr[4], d0i=vi[0]-vi[4];
            float t1r=vr[1]+vr[5], t1i=vi[1]+vi[5];
            float d1r=vr[1]-vr[5], d1i=vi[1]-vi[5];
            float t2r=vr[2]+vr[6], t2i=vi[2]+vi[6];
            float d2r=vr[2]-vr[6], d2i=vi[2]-vi[6];
            float t3r=vr[3]+vr[7], t3i=vi[3]+vi[7];
            float d3r=vr[3]-vr[7], d3i=vi[3]-vi[7];
            vr[0]=t0r; vi[0]=t0i; vr[1]=t1r; vi[1]=t1i;
            vr[2]=t2r; vi[2]=t2i; vr[3]=t3r; vi[3]=t3i;
            vr[4]=d0r;                 vi[4]=d0i;                  // *1
            vr[5]=(d1r+d1i)*RH;        vi[5]=(d1i-d1r)*RH;         // *W8^1
            vr[6]=d2i;                 vi[6]=-d2r;                 // *(-i)
            vr[7]=(d3i-d3r)*RH;        vi[7]=-(d3r+d3i)*RH;        // *W8^3
        }
        {   // stage M=4 on each half, twiddles {1, -i}
            float t0r=vr[0]+vr[2], t0i=vi[0]+vi[2];
            float d0r=vr[0]-vr[2], d0i=vi[0]-vi[2];
            float t1r=vr[1]+vr[3], t1i=vi[1]+vi[3];
            float d1r=vr[1]-vr[3], d1i=vi[1]-vi[3];
            vr[0]=t0r; vi[0]=t0i; vr[1]=t1r; vi[1]=t1i;
            vr[2]=d0r; vi[2]=d0i; vr[3]=d1i; vi[3]=-d1r;
            float t4r=vr[4]+vr[6], t4i=vi[4]+vi[6];
            float d4r=vr[4]-vr[6], d4i=vi[4]-vi[6];
            float t5r=vr[5]+vr[7], t5i=vi[5]+vi[7];
            float d5r=vr[5]-vr[7], d5i=vi[5]-vi[7];
            vr[4]=t4r; vi[4]=t4i; vr[5]=t5r; vi[5]=t5i;
            vr[6]=d4r; vi[6]=d4i; vr[7]=d5i; vi[7]=-d5r;
        }
        {   // stage M=2, no twiddles
            float t0r=vr[0]+vr[1], t0i=vi[0]+vi[1];
            float d0r=vr[0]-vr[1], d0i=vi[0]-vi[1];
            vr[0]=t0r; vi[0]=t0i; vr[1]=d0r; vi[1]=d0i;
            float t2r=vr[2]+vr[3], t2i=vi[2]+vi[3];
            float d2r=vr[2]-vr[3], d2i=vi[2]-vi[3];
            vr[2]=t2r; vi[2]=t2i; vr[3]=d2r; vi[3]=d2i;
            float t4r=vr[4]+vr[5], t4i=vi[4]+vi[5];
            float d4r=vr[4]-vr[5], d4i=vi[4]-vi[5];
            vr[4]=t4r; vi[4]=t4i; vr[5]=d4r; vi[5]=d4i;
            float t6r=vr[6]+vr[7], t6i=vi[6]+vi[7];
            float d6r=vr[6]-vr[7], d6i=vi[6]-vi[7];
            vr[6]=t6r; vi[6]=t6i; vr[7]=d6r; vi[7]=d6i;
        }
        // reg p holds X[rev6(l) + 64*rev3(p)]; only k2<=3 (+bin 256) needed

        // ---- power spectrum -> LDS (natural order, conflict-free) ----
        const float scale = 1.0f / 512.0f;
        pwrow[rl      ] = (vr[0]*vr[0] + vi[0]*vi[0]) * scale;  // k2=0
        pwrow[rl +  64] = (vr[4]*vr[4] + vi[4]*vi[4]) * scale;  // k2=1
        pwrow[rl + 128] = (vr[2]*vr[2] + vi[2]*vi[2]) * scale;  // k2=2
        pwrow[rl + 192] = (vr[6]*vr[6] + vi[6]*vi[6]) * scale;  // k2=3
        if (l == 0)
            pwrow[256] = (vr[1]*vr[1] + vi[1]*vi[1]) * scale;   // k1=0,k2=4

        asm volatile("s_waitcnt lgkmcnt(0)" ::: "memory");      // wave-local fence

        // ---- sparse mel matmul: lane l = filter l, <=24-bin window ----
        float acc = 1e-30f;
#pragma unroll
        for (int i = 0; i < WMAX; i++)
            acc = fmaf(wc[i], pwrow[lo + i], acc);

        // ---- per-frame mean/std over the 64 filters ----
        float sum = acc;
#pragma unroll
        for (int mk = 1; mk < 64; mk <<= 1) sum += __shfl_xor(sum, mk, 64);
        const float mean = sum * (1.0f / 64.0f);
        const float dd = acc - mean;
        float v2 = dd * dd;
#pragma unroll
        for (int mk = 1; mk < 64; mk <<= 1) v2 += __shfl_xor(v2, mk, 64);
        const float sd = sqrtf(v2 * (1.0f / 64.0f));
        out[f * NFILT + l] = dd / sd;
    }
}

extern "C" void kernel_launch(void* const* d_in, const int* in_sizes, int n_in,
                              void* d_out, int out_size, void* d_ws, size_t ws_size,
                              hipStream_t stream) {
    (void)d_ws; (void)ws_size; (void)n_in; (void)in_sizes;
    const float* x = (const float*)d_in[0];
    const float* filters = (const float*)d_in[1];
    float* out = (float*)d_out;
    const int num_frames = out_size / NFILT;
    const int total_waves = NBLOCKS * WAVES;
    const int fpw = (num_frames + total_waves - 1) / total_waves;
    fbank_kernel<<<NBLOCKS, 256, 0, stream>>>(x, filters, out, num_frames, fpw);
}

// Round 3
// 102.481 us; speedup vs baseline: 2.9279x; 1.0918x over previous
//
#include <hip/hip_runtime.h>
#include <math.h>

#define NFILT 64
#define FRAME_LEN 400
#define FRAME_STEP 160
#define WMAX 24            // max nonzero span of one mel filter (verified <= 24 in R1/R2)
#define WSTRIDE 25         // padded stride: gcd(25,32)=1 -> conflict-free lane-indexed reads
#define WAVES 4
#define NBLOCKS 1563       // 6252 waves x 4 pairs = 25008 pair slots for 25000 pairs
#define PWBINS 280         // 257 bins + pad for window overrun

// One wave computes TWO frames per iteration: z = frame_a + i*frame_b through a
// single 512-pt FFT (per-lane radix-8 x cross-lane 64-pt shuffle FFT), then the
// conjugate-symmetry untangle recovers both power spectra. No __syncthreads in
// the main loop; LDS holds the shared filter windows + per-wave power spectrum.
__global__ __launch_bounds__(256) void fbank_kernel(const float* __restrict__ x,
                                                    const float* __restrict__ filters,
                                                    float* __restrict__ out,
                                                    int num_frames) {
    __shared__ float wc_lds[NFILT * WSTRIDE];
    __shared__ int   lo_lds[NFILT];
    __shared__ float pw[WAVES][PWBINS * 2];   // interleaved (pa, pb) per bin

    const int t = threadIdx.x;
    const int l = t & 63;              // lane
    const int w = t >> 6;              // wave in block
    float* pwrow = pw[w];

    // zero this wave's pad bins [257, PWBINS) once; never rewritten
    if (l < 2 * (PWBINS - 257)) pwrow[2 * 257 + l] = 0.0f;

    // ---- wave 0: find each filter's window and stage weights into LDS ----
    if (w == 0) {
        int lo = 257;
        for (int k = 0; k < 257; k++) {
            float fv = filters[k * NFILT + l];
            if (fv != 0.0f && lo == 257) lo = k;
        }
        if (lo > 256) lo = 256;        // all-zero column safety
        lo_lds[l] = lo;
        for (int i = 0; i < WMAX; i++) {
            int k = lo + i;
            wc_lds[l * WSTRIDE + i] = (k <= 256) ? filters[k * NFILT + l] : 0.0f;
        }
    }

    // ---- loop-invariant twiddles (registers) ----
    const int rl = (int)(__brev((unsigned)l) >> 26);    // rev6(lane) = k1
    float cA[6], sA[6], sg[6];
#pragma unroll
    for (int j = 0; j < 6; j++) {
        const int d = 32 >> j;
        const int hi = l & d;
        float th = -2.0f * (float)M_PI * (float)(l & (d - 1)) / (float)(2 * d);
        cA[j] = hi ? cosf(th) : 1.0f;
        sA[j] = hi ? sinf(th) : 0.0f;
        sg[j] = hi ? -1.0f : 1.0f;
    }
    float br[8], bi[8];                 // W_512^{n2*k1}
    {
        float th = -2.0f * (float)M_PI * (float)rl * (1.0f / 512.0f);
        float c1 = cosf(th), s1 = sinf(th);
        br[0] = 1.0f; bi[0] = 0.0f; br[1] = c1; bi[1] = s1;
#pragma unroll
        for (int r = 2; r < 8; r++) {
            float pr_ = br[r - 1], pi_ = bi[r - 1];
            br[r] = pr_ * c1 - pi_ * s1;
            bi[r] = pr_ * s1 + pi_ * c1;
        }
    }
    // conj partner lane: holds rl' = (64 - rl) & 63
    const int Lp = (int)(__brev((unsigned)((64 - rl) & 63)) >> 26);

    __syncthreads();
    const int lo = lo_lds[l];

    const int gw = blockIdx.x * WAVES + w;
    const int totw = gridDim.x * WAVES;
    const int npairs = (num_frames + 1) >> 1;

    for (int pair = gw; pair < npairs; pair += totw) {
        const long fa = 2L * pair;
        const bool hasb = (fa + 1) < num_frames;
        const long ba = fa * FRAME_STEP;
        const long bb = ba + FRAME_STEP;

        // ---- load + pre-emphasis: frame a -> vr, frame b -> vi ----
        float vr[8], vi[8];
        {
            float a0=0,a1=0,a2=0,a3=0,a4=0,a5=0,a6=0,a7=0;
            if (l < 50) {
                const float4* p4 = reinterpret_cast<const float4*>(x + ba + 8 * l);
                float4 A = p4[0], B = p4[1];
                a0=A.x; a1=A.y; a2=A.z; a3=A.w; a4=B.x; a5=B.y; a6=B.z; a7=B.w;
            }
            float ev = x[ba > 0 ? ba - 1 : 0];
            float edge = (ba > 0) ? ev : 0.0f;     // pre[0] = x[0] - 0.97*0
            float prev = __shfl_up(a7, 1, 64);
            if (l == 0) prev = edge;
            vr[0] = (l < 50) ? fmaf(-0.97f, prev, a0) : 0.0f;
            vr[1] = (l < 50) ? fmaf(-0.97f, a0, a1) : 0.0f;
            vr[2] = (l < 50) ? fmaf(-0.97f, a1, a2) : 0.0f;
            vr[3] = (l < 50) ? fmaf(-0.97f, a2, a3) : 0.0f;
            vr[4] = (l < 50) ? fmaf(-0.97f, a3, a4) : 0.0f;
            vr[5] = (l < 50) ? fmaf(-0.97f, a4, a5) : 0.0f;
            vr[6] = (l < 50) ? fmaf(-0.97f, a5, a6) : 0.0f;
            vr[7] = (l < 50) ? fmaf(-0.97f, a6, a7) : 0.0f;
        }
        {
            float b0=0,b1=0,b2=0,b3=0,b4=0,b5=0,b6=0,b7=0;
            if (hasb && l < 50) {
                const float4* p4 = reinterpret_cast<const float4*>(x + bb + 8 * l);
                float4 A = p4[0], B = p4[1];
                b0=A.x; b1=A.y; b2=A.z; b3=A.w; b4=B.x; b5=B.y; b6=B.z; b7=B.w;
            }
            float edge = hasb ? x[bb - 1] : 0.0f;  // bb >= 160 always
            float prev = __shfl_up(b7, 1, 64);
            if (l == 0) prev = edge;
            vi[0] = (l < 50) ? fmaf(-0.97f, prev, b0) : 0.0f;
            vi[1] = (l < 50) ? fmaf(-0.97f, b0, b1) : 0.0f;
            vi[2] = (l < 50) ? fmaf(-0.97f, b1, b2) : 0.0f;
            vi[3] = (l < 50) ? fmaf(-0.97f, b2, b3) : 0.0f;
            vi[4] = (l < 50) ? fmaf(-0.97f, b3, b4) : 0.0f;
            vi[5] = (l < 50) ? fmaf(-0.97f, b4, b5) : 0.0f;
            vi[6] = (l < 50) ? fmaf(-0.97f, b5, b6) : 0.0f;
            vi[7] = (l < 50) ? fmaf(-0.97f, b6, b7) : 0.0f;
        }

        // ---- cross-lane 64-pt DIF FFT (6 shuffle stages, complex) ----
#pragma unroll
        for (int j = 0; j < 6; j++) {
            const int d = 32 >> j;
            const float c = cA[j], s = sA[j], g = sg[j];
#pragma unroll
            for (int r = 0; r < 8; r++) {
                float pr = __shfl_xor(vr[r], d, 64);
                float pi = __shfl_xor(vi[r], d, 64);
                float tr = fmaf(g, vr[r], pr);
                float ti = fmaf(g, vi[r], pi);
                vr[r] = tr * c - ti * s;
                vi[r] = tr * s + ti * c;
            }
        }
        // lane l holds A[k1 = rev6(l)] per sample-group n2 = r

        // ---- twiddle W_512^{n2*k1} ----
#pragma unroll
        for (int r = 1; r < 8; r++) {
            float tr = vr[r], ti = vi[r];
            vr[r] = tr * br[r] - ti * bi[r];
            vi[r] = tr * bi[r] + ti * br[r];
        }

        // ---- in-register 8-pt DIF FFT over n2 ----
        const float RH = 0.70710678118654752f;
        {
            float t0r=vr[0]+vr[4], t0i=vi[0]+vi[4];
            float d0r=vr[0]-vr[4], d0i=vi[0]-vi[4];
            float t1r=vr[1]+vr[5], t1i=vi[1]+vi[5];
            float d1r=vr[1]-vr[5], d1i=vi[1]-vi[5];
            float t2r=vr[2]+vr[6], t2i=vi[2]+vi[6];
            float d2r=vr[2]-vr[6], d2i=vi[2]-vi[6];
            float t3r=vr[3]+vr[7], t3i=vi[3]+vi[7];
            float d3r=vr[3]-vr[7], d3i=vi[3]-vi[7];
            vr[0]=t0r; vi[0]=t0i; vr[1]=t1r; vi[1]=t1i;
            vr[2]=t2r; vi[2]=t2i; vr[3]=t3r; vi[3]=t3i;
            vr[4]=d0r;                 vi[4]=d0i;
            vr[5]=(d1r+d1i)*RH;        vi[5]=(d1i-d1r)*RH;
            vr[6]=d2i;                 vi[6]=-d2r;
            vr[7]=(d3i-d3r)*RH;        vi[7]=-(d3r+d3i)*RH;
        }
        {
            float t0r=vr[0]+vr[2], t0i=vi[0]+vi[2];
            float d0r=vr[0]-vr[2], d0i=vi[0]-vi[2];
            float t1r=vr[1]+vr[3], t1i=vi[1]+vi[3];
            float d1r=vr[1]-vr[3], d1i=vi[1]-vi[3];
            vr[0]=t0r; vi[0]=t0i; vr[1]=t1r; vi[1]=t1i;
            vr[2]=d0r; vi[2]=d0i; vr[3]=d1i; vi[3]=-d1r;
            float t4r=vr[4]+vr[6], t4i=vi[4]+vi[6];
            float d4r=vr[4]-vr[6], d4i=vi[4]-vi[6];
            float t5r=vr[5]+vr[7], t5i=vi[5]+vi[7];
            float d5r=vr[5]-vr[7], d5i=vi[5]-vi[7];
            vr[4]=t4r; vi[4]=t4i; vr[5]=t5r; vi[5]=t5i;
            vr[6]=d4r; vi[6]=d4i; vr[7]=d5i; vi[7]=-d5r;
        }
        {
            float t0r=vr[0]+vr[1], t0i=vi[0]+vi[1];
            float d0r=vr[0]-vr[1], d0i=vi[0]-vi[1];
            vr[0]=t0r; vi[0]=t0i; vr[1]=d0r; vi[1]=d0i;
            float t2r=vr[2]+vr[3], t2i=vi[2]+vi[3];
            float d2r=vr[2]-vr[3], d2i=vi[2]-vi[3];
            vr[2]=t2r; vi[2]=t2i; vr[3]=d2r; vi[3]=d2i;
            float t4r=vr[4]+vr[5], t4i=vi[4]+vi[5];
            float d4r=vr[4]-vr[5], d4i=vi[4]-vi[5];
            vr[4]=t4r; vi[4]=t4i; vr[5]=d4r; vi[5]=d4i;
            float t6r=vr[6]+vr[7], t6i=vi[6]+vi[7];
            float d6r=vr[6]-vr[7], d6i=vi[6]-vi[7];
            vr[6]=t6r; vi[6]=t6i; vr[7]=d6r; vi[7]=d6i;
        }
        // reg p holds Z[rev6(l) + 64*rev3(p)]; needed bins: k2=0..3 in p={0,4,2,6},
        // plus bin 256 = lane 0's p=1.

        // ---- conjugate-symmetry untangle: Zc[k] = Z[512-k] ----
        // partner of (rl, k2) is (64-rl, 7-k2) i.e. (lane Lp, reg 7-p); lane 0
        // (rl=0) pairs with itself at reg rev3((8-k2)&7).
        float c0r = __shfl(vr[7], Lp, 64), c0i = __shfl(vi[7], Lp, 64);  // p=0
        float c1r = __shfl(vr[3], Lp, 64), c1i = __shfl(vi[3], Lp, 64);  // p=4
        float c2r = __shfl(vr[5], Lp, 64), c2i = __shfl(vi[5], Lp, 64);  // p=2
        float c3r = __shfl(vr[1], Lp, 64), c3i = __shfl(vi[1], Lp, 64);  // p=6
        if (l == 0) {
            c0r = vr[0]; c0i = vi[0];   // bin 0   <- Z[0]
            c1r = vr[7]; c1i = vi[7];   // bin 64  <- Z[448]
            c2r = vr[3]; c2i = vi[3];   // bin 128 <- Z[384]
            c3r = vr[5]; c3i = vi[5];   // bin 192 <- Z[320]
        }

        // ---- untangle + power -> LDS (interleaved a,b) ----
        const float S4 = (1.0f / 512.0f) * 0.25f;
        {
            float zr = vr[0], zi = vi[0];
            float e1 = zr + c0r, e2 = zi - c0i, o1 = zi + c0i, o2 = c0r - zr;
            float2 pq = make_float2((e1*e1 + e2*e2) * S4, (o1*o1 + o2*o2) * S4);
            *reinterpret_cast<float2*>(&pwrow[2 * rl]) = pq;
        }
        {
            float zr = vr[4], zi = vi[4];
            float e1 = zr + c1r, e2 = zi - c1i, o1 = zi + c1i, o2 = c1r - zr;
            float2 pq = make_float2((e1*e1 + e2*e2) * S4, (o1*o1 + o2*o2) * S4);
            *reinterpret_cast<float2*>(&pwrow[2 * (rl + 64)]) = pq;
        }
        {
            float zr = vr[2], zi = vi[2];
            float e1 = zr + c2r, e2 = zi - c2i, o1 = zi + c2i, o2 = c2r - zr;
            float2 pq = make_float2((e1*e1 + e2*e2) * S4, (o1*o1 + o2*o2) * S4);
            *reinterpret_cast<float2*>(&pwrow[2 * (rl + 128)]) = pq;
        }
        {
            float zr = vr[6], zi = vi[6];
            float e1 = zr + c3r, e2 = zi - c3i, o1 = zi + c3i, o2 = c3r - zr;
            float2 pq = make_float2((e1*e1 + e2*e2) * S4, (o1*o1 + o2*o2) * S4);
            *reinterpret_cast<float2*>(&pwrow[2 * (rl + 192)]) = pq;
        }
        if (l == 0) {   // bin 256 pairs with itself: Xa=Re(Z[256]), Xb=Im(Z[256])
            pwrow[512] = vr[1] * vr[1] * (1.0f / 512.0f);
            pwrow[513] = vi[1] * vi[1] * (1.0f / 512.0f);
        }

        asm volatile("s_waitcnt lgkmcnt(0)" ::: "memory");  // wave-local fence

        // ---- sparse mel matmul, both frames per ds_read_b64 ----
        float acca = 1e-30f, accb = 1e-30f;
#pragma unroll
        for (int i = 0; i < WMAX; i++) {
            float wv = wc_lds[l * WSTRIDE + i];
            float2 pq = *reinterpret_cast<const float2*>(&pwrow[2 * (lo + i)]);
            acca = fmaf(wv, pq.x, acca);
            accb = fmaf(wv, pq.y, accb);
        }

        // ---- per-frame normalize (independent chains, interleaved) ----
        float sa = acca, sb = accb;
#pragma unroll
        for (int mk = 1; mk < 64; mk <<= 1) {
            sa += __shfl_xor(sa, mk, 64);
            sb += __shfl_xor(sb, mk, 64);
        }
        const float ma = sa * (1.0f / 64.0f), mb = sb * (1.0f / 64.0f);
        const float da = acca - ma, db = accb - mb;
        float va = da * da, vb = db * db;
#pragma unroll
        for (int mk = 1; mk < 64; mk <<= 1) {
            va += __shfl_xor(va, mk, 64);
            vb += __shfl_xor(vb, mk, 64);
        }
        out[fa * NFILT + l] = da / sqrtf(va * (1.0f / 64.0f));
        if (hasb)
            out[(fa + 1) * NFILT + l] = db / sqrtf(vb * (1.0f / 64.0f));
    }
}

extern "C" void kernel_launch(void* const* d_in, const int* in_sizes, int n_in,
                              void* d_out, int out_size, void* d_ws, size_t ws_size,
                              hipStream_t stream) {
    (void)d_ws; (void)ws_size; (void)n_in; (void)in_sizes;
    const float* x = (const float*)d_in[0];
    const float* filters = (const float*)d_in[1];
    float* out = (float*)d_out;
    const int num_frames = out_size / NFILT;
    fbank_kernel<<<NBLOCKS, 256, 0, stream>>>(x, filters, out, num_frames);
}